// Round 6
// baseline (616.355 us; speedup 1.0000x reference)
//
#include <hip/hip_runtime.h>
#include <hip/hip_bf16.h>
#include <stdint.h>
#include <math.h>

#define B_ 2
#define S_ 2048
#define E_ 2048
#define H_ 16
#define D_ 128
#define M_ (B_*S_)

typedef _Float16 half8 __attribute__((ext_vector_type(8)));
typedef _Float16 half4 __attribute__((ext_vector_type(4)));
typedef _Float16 half2v __attribute__((ext_vector_type(2)));
typedef float    floatx4 __attribute__((ext_vector_type(4)));

// ---------------------------------------------------------------------------
// async global->LDS, 16B per lane. LDS dest must be wave-uniform base; HW
// writes lane L at base + L*16.
__device__ __forceinline__ void async_copy16(const void* g, void* lds_base) {
    __builtin_amdgcn_global_load_lds(
        (__attribute__((address_space(1))) void*)(uintptr_t)g,
        (__attribute__((address_space(3))) void*)(uint32_t)(uintptr_t)lds_base,
        16, 0, 0);
}

// ---------------------------------------------------------------------------
// fused fp32 -> fp16 cast for X + 4 weights, one launch (z selects tensor)
__global__ __launch_bounds__(256) void cast_all(
    const float* __restrict__ X,  const float* __restrict__ Wq,
    const float* __restrict__ Wk, const float* __restrict__ Wv,
    const float* __restrict__ Wo,
    _Float16* __restrict__ Xh,  _Float16* __restrict__ Wqh,
    _Float16* __restrict__ Wkh, _Float16* __restrict__ Wvh,
    _Float16* __restrict__ Woh)
{
    const int z = blockIdx.z;
    const float* in; _Float16* out; int n4;
    const int ME4 = M_*E_/4, EE4 = E_*E_/4;
    switch (z) {
        case 0: in = X;  out = Xh;  n4 = ME4; break;
        case 1: in = Wq; out = Wqh; n4 = EE4; break;
        case 2: in = Wk; out = Wkh; n4 = EE4; break;
        case 3: in = Wv; out = Wvh; n4 = EE4; break;
        default: in = Wo; out = Woh; n4 = EE4; break;
    }
    int i = blockIdx.x * 256 + threadIdx.x;
    if (i < n4) {
        floatx4 v = ((const floatx4*)in)[i];
        ((half4*)out)[i] = __builtin_convertvector(v, half4);
    }
}

// ---------------------------------------------------------------------------
// C[M,N] = A[M,K] · W[N,K]^T  (both K-contiguous row-major), f16 MFMA,
// m97 structure: 128x128 tile, BK=32, global_load_lds width=16.
template<bool BIAS, typename OutT, int NW>
__global__ __launch_bounds__(256) void gemm_bt(
    const _Float16* __restrict__ A,
    const _Float16* __restrict__ W0, const _Float16* __restrict__ W1,
    const _Float16* __restrict__ W2,
    OutT* __restrict__ C0, OutT* __restrict__ C1, OutT* __restrict__ C2,
    const float* __restrict__ bias, int M, int N, int K)
{
    const _Float16* W = W0; OutT* C = C0;
    if (NW > 1) {
        if (blockIdx.z == 1) { W = W1; C = C1; }
        else if (blockIdx.z == 2) { W = W2; C = C2; }
    }
    __shared__ __align__(16) _Float16 As[128*32];
    __shared__ __align__(16) _Float16 Bs[128*32];
    const int tid  = threadIdx.x;
    const int lane = tid & 63;
    const int wave = tid >> 6;
    const int wm = wave >> 1, wn = wave & 1;      // 2x2 waves, 64x64 each
    const int fr = lane & 15, fg = lane >> 4;
    const int m0 = blockIdx.x * 128;
    const int n0 = blockIdx.y * 128;

    floatx4 acc[4][4] = {};

    for (int k0 = 0; k0 < K; k0 += 32) {
        __syncthreads();
#pragma unroll
        for (int i = 0; i < 2; ++i) {
            int c = wave * 2 + i;
            int e = c * 512 + lane * 8;           // element index in [128][32] tile
            int row = e >> 5, col = e & 31;
            async_copy16(A + (size_t)(m0 + row) * K + k0 + col, &As[c * 512]);
            async_copy16(W + (size_t)(n0 + row) * K + k0 + col, &Bs[c * 512]);
        }
        __syncthreads();

        half8 a[4], b[4];
#pragma unroll
        for (int t = 0; t < 4; ++t) {
            a[t] = *(const half8*)&As[(wm*64 + t*16 + fr) * 32 + fg*8];
            b[t] = *(const half8*)&Bs[(wn*64 + t*16 + fr) * 32 + fg*8];
        }
#pragma unroll
        for (int mt = 0; mt < 4; ++mt)
#pragma unroll
            for (int nt = 0; nt < 4; ++nt)
                acc[mt][nt] = __builtin_amdgcn_mfma_f32_16x16x32_f16(
                    a[mt], b[nt], acc[mt][nt], 0, 0, 0);
    }

#pragma unroll
    for (int mt = 0; mt < 4; ++mt)
#pragma unroll
        for (int nt = 0; nt < 4; ++nt) {
            int col = n0 + wn*64 + nt*16 + fr;
            float bv = BIAS ? bias[col] : 0.f;
#pragma unroll
            for (int r = 0; r < 4; ++r) {
                int row = m0 + wm*64 + mt*16 + fg*4 + r;
                C[(size_t)row * N + col] = (OutT)(acc[mt][nt][r] + bv);
            }
        }
}

// ---------------------------------------------------------------------------
// V [B,S,H*D] (f16) -> Vt2 [B*H, D, S] (f16) with chunk-interleaved s-index:
// within each 32-block of s, element s (= c0*16 + g*4 + j, g=quad, j=0..3)
// is stored at position g*8 + c0*4 + j. This makes the 16x16x16 PV B-operand
// fragments for two adjacent 16-chunks one contiguous 16B load.
__global__ __launch_bounds__(256) void transpose_v(
    const _Float16* __restrict__ V, _Float16* __restrict__ Vt)
{
    __shared__ __align__(16) _Float16 t[64][72];
    const int bh = blockIdx.z;
    const int b = bh >> 4, h = bh & 15;
    const int s0 = blockIdx.x * 64, d0 = blockIdx.y * 64;
    const int tid = threadIdx.x;
#pragma unroll
    for (int i = 0; i < 2; ++i) {
        int e = (i*256 + tid) * 8;
        int row = e >> 6, col = e & 63;           // row = s, col = d
        *(half8*)&t[row][col] =
            *(const half8*)&V[(size_t)(b*S_ + s0 + row) * E_ + h*D_ + d0 + col];
    }
    __syncthreads();
#pragma unroll
    for (int i = 0; i < 2; ++i) {
        int e = (i*256 + tid) * 8;
        int dr = e >> 6, col = e & 63;            // dr = d, col = s (mult of 8)
        half4 vlo, vhi;
#pragma unroll
        for (int j = 0; j < 4; ++j) { vlo[j] = t[col + j][dr]; vhi[j] = t[col + 4 + j][dr]; }
        const int g  = (col >> 2) & 3;            // 0 or 2
        const int c0 = (col >> 4) & 1;
        _Float16* ob = &Vt[((size_t)bh * D_ + d0 + dr) * S_ + s0 + (col & ~31)];
        *(half4*)&ob[g*8 + c0*4]       = vlo;
        *(half4*)&ob[(g+1)*8 + c0*4]   = vhi;
    }
}

// ---------------------------------------------------------------------------
// Paired, ks-split causal flash attention. Block = 128 threads = 2 waves.
// Block owns q-strips t0 = p and t1 = 127-p (16 rows each, same bh) -> every
// block does 33-34 tile-iterations (perfect balance, no triangular drain).
// Wave w handles jt = w, w+2, ... (ks-split); fixed-max softmax makes the
// two waves' (O_num, l) partials ADDITIVE -> one LDS merge + one barrier at
// the very end. For jt < n0 both q-tiles consume the SAME kf/vf fragments.
// S^T = K·Q^T trick (round 4): P exits QK in PV A-operand layout; exp only,
// no LDS round-trip in the loop.
__global__ __launch_bounds__(128, 3) void attn_pair(
    const _Float16* __restrict__ Q, const _Float16* __restrict__ K,
    const _Float16* __restrict__ Vt, _Float16* __restrict__ O)
{
    const int bx = blockIdx.x;
    const int bh = (bx & 7) * 4 + ((bx >> 3) & 3);  // 4 heads per XCD slot
    const int p  = bx >> 5;                          // 0..63
    const int b = bh >> 4, h = bh & 15;
    const int tid = threadIdx.x;
    const int w = tid >> 6;                          // wave 0/1
    const int lane = tid & 63, fr = lane & 15, fg = lane >> 4;

    const int t0 = p, t1 = 127 - p;                  // 16-row strip indices
    const int n0 = (t0 >> 2) + 1, n1 = (t1 >> 2) + 1; // 64-ks tiles needed
    const int dg0 = n0 - 1, dg1 = n1 - 1;

    __shared__ __align__(16) float redo[2*8*64*4];   // 16 KB merge buffer
    __shared__ float redl[2*64];

    // Q fragments (B-operand of K·Q^T): [n=fr][k=fg*8+j]
    half8 qf[2][4];
    {
        const _Float16* qb0 = Q + ((size_t)(b*S_) + t0*16) * E_ + h*D_;
        const _Float16* qb1 = Q + ((size_t)(b*S_) + t1*16) * E_ + h*D_;
#pragma unroll
        for (int kk = 0; kk < 4; ++kk) {
            qf[0][kk] = *(const half8*)&qb0[(size_t)fr * E_ + kk*32 + fg*8];
            qf[1][kk] = *(const half8*)&qb1[(size_t)fr * E_ + kk*32 + fg*8];
        }
    }

    const _Float16* kb = K + (size_t)(b*S_) * E_ + h*D_;
    const _Float16* vb = Vt + (size_t)bh * D_ * S_;

    floatx4 o[2][8] = {};
    float lsum[2] = {0.f, 0.f};
    const float kSC = 0.088388347648318447f * 1.4426950408889634f; // /sqrt(D)*log2e

    for (int jt = w; jt < n1; jt += 2) {
        const bool both = jt < n0;

        // ---- S^T = K·Q^T (shared kf between the two q-tiles) -------------
        floatx4 st[2][4] = {};
#pragma unroll
        for (int kk = 0; kk < 4; ++kk) {
            half8 kf[4];
#pragma unroll
            for (int mtk = 0; mtk < 4; ++mtk)
                kf[mtk] = *(const half8*)&kb[(size_t)(jt*64 + mtk*16 + fr) * E_ + kk*32 + fg*8];
#pragma unroll
            for (int mtk = 0; mtk < 4; ++mtk)
                st[1][mtk] = __builtin_amdgcn_mfma_f32_16x16x32_f16(
                    kf[mtk], qf[1][kk], st[1][mtk], 0, 0, 0);
            if (both) {
#pragma unroll
                for (int mtk = 0; mtk < 4; ++mtk)
                    st[0][mtk] = __builtin_amdgcn_mfma_f32_16x16x32_f16(
                        kf[mtk], qf[0][kk], st[0][mtk], 0, 0, 0);
            }
        }

        // ---- softmax numerator (fixed max) + pack to PV A-fragments ------
        half4 pf[2][4];
#pragma unroll
        for (int tile = 0; tile < 2; ++tile) {
            if (tile == 0 && !both) continue;     // skip ONLY tile 0 (bugfix)
            const int tt = (tile == 0) ? t0 : t1;
            const int dg = (tile == 0) ? dg0 : dg1;
#pragma unroll
            for (int mtk = 0; mtk < 4; ++mtk) {
                float pv[4];
#pragma unroll
                for (int r = 0; r < 4; ++r)
                    pv[r] = exp2f(st[tile][mtk][r] * kSC);
                if (jt == dg) {                   // mask only on diagonal tile
                    int ksb = jt*64 + mtk*16 + fg*4;
                    int qv  = tt*16 + fr;
#pragma unroll
                    for (int r = 0; r < 4; ++r)
                        pv[r] = (ksb + r <= qv) ? pv[r] : 0.f;
                }
                lsum[tile] += (pv[0] + pv[1]) + (pv[2] + pv[3]);
                half2v a01 = __builtin_bit_cast(half2v, __builtin_amdgcn_cvt_pkrtz(pv[0], pv[1]));
                half2v a23 = __builtin_bit_cast(half2v, __builtin_amdgcn_cvt_pkrtz(pv[2], pv[3]));
                half4 pa; pa[0]=a01[0]; pa[1]=a01[1]; pa[2]=a23[0]; pa[3]=a23[1];
                pf[tile][mtk] = pa;
            }
        }

        // ---- O += P·V (shared vf; Vt2 chunk-interleaved b128) ------------
#pragma unroll
        for (int c2 = 0; c2 < 2; ++c2)
#pragma unroll
            for (int dt = 0; dt < 8; ++dt) {
                half8 vf = *(const half8*)&vb[(size_t)(dt*16 + fr) * S_ + jt*64 + c2*32 + fg*8];
                half4 vlo = __builtin_shufflevector(vf, vf, 0, 1, 2, 3);
                half4 vhi = __builtin_shufflevector(vf, vf, 4, 5, 6, 7);
                o[1][dt] = __builtin_amdgcn_mfma_f32_16x16x16f16(
                    pf[1][c2*2],     vlo, o[1][dt], 0, 0, 0);
                o[1][dt] = __builtin_amdgcn_mfma_f32_16x16x16f16(
                    pf[1][c2*2 + 1], vhi, o[1][dt], 0, 0, 0);
                if (both) {
                    o[0][dt] = __builtin_amdgcn_mfma_f32_16x16x16f16(
                        pf[0][c2*2],     vlo, o[0][dt], 0, 0, 0);
                    o[0][dt] = __builtin_amdgcn_mfma_f32_16x16x16f16(
                        pf[0][c2*2 + 1], vhi, o[0][dt], 0, 0, 0);
                }
            }
    }

    // ---- merge the two waves' additive partials, then store --------------
    if (w == 1) {
#pragma unroll
        for (int tile = 0; tile < 2; ++tile)
#pragma unroll
            for (int dt = 0; dt < 8; ++dt)
                *(floatx4*)&redo[((tile*8 + dt)*64 + lane)*4] = o[tile][dt];
        redl[lane]      = lsum[0];
        redl[64 + lane] = lsum[1];
    }
    __syncthreads();
    if (w == 0) {
#pragma unroll
        for (int tile = 0; tile < 2; ++tile) {
#pragma unroll
            for (int dt = 0; dt < 8; ++dt)
                o[tile][dt] += *(const floatx4*)&redo[((tile*8 + dt)*64 + lane)*4];
            float l = lsum[tile] + redl[tile*64 + lane];
            l += __shfl_xor(l, 16);
            l += __shfl_xor(l, 32);              // all lanes: total l for q=fr
            float inv[4];
#pragma unroll
            for (int r = 0; r < 4; ++r)
                inv[r] = 1.f / __shfl(l, fg*4 + r);  // re-index to C-layout rows
            const int tt = (tile == 0) ? t0 : t1;
            _Float16* ob = O + ((size_t)(b*S_) + tt*16) * E_ + h*D_;
#pragma unroll
            for (int r = 0; r < 4; ++r)
#pragma unroll
                for (int dt = 0; dt < 8; ++dt)
                    ob[(size_t)(fg*4 + r) * E_ + dt*16 + fr] =
                        (_Float16)(o[tile][dt][r] * inv[r]);
        }
    }
}

// ---------------------------------------------------------------------------
extern "C" void kernel_launch(void* const* d_in, const int* in_sizes, int n_in,
                              void* d_out, int out_size, void* d_ws, size_t ws_size,
                              hipStream_t stream) {
    const float* X  = (const float*)d_in[0];
    const float* Wq = (const float*)d_in[1];
    const float* Wk = (const float*)d_in[2];
    const float* Wv = (const float*)d_in[3];
    const float* Wo = (const float*)d_in[4];
    const float* bo = (const float*)d_in[5];
    float* out = (float*)d_out;

    const size_t ME = (size_t)M_ * E_;   // 8,388,608
    const size_t EE = (size_t)E_ * E_;   // 4,194,304
    _Float16* ws  = (_Float16*)d_ws;
    _Float16* Xh  = ws;
    _Float16* Wqh = Xh  + ME;
    _Float16* Wkh = Wqh + EE;
    _Float16* Wvh = Wkh + EE;
    _Float16* Woh = Wvh + EE;
    _Float16* Qh  = Woh + EE;
    _Float16* Kh  = Qh  + ME;
    _Float16* Vh  = Kh  + ME;
    _Float16* Vth = Xh;   // Xh dead after the QKV GEMMs
    _Float16* Oh  = Vh;   // V dead after the transpose

    cast_all<<<dim3(ME/4/256, 1, 5), dim3(256), 0, stream>>>(
        X, Wq, Wk, Wv, Wo, Xh, Wqh, Wkh, Wvh, Woh);

    gemm_bt<false, _Float16, 3><<<dim3(M_/128, E_/128, 3), dim3(256), 0, stream>>>(
        Xh, Wqh, Wkh, Wvh, Qh, Kh, Vh, nullptr, M_, E_, E_);

    transpose_v<<<dim3(S_/64, D_/64, B_*H_), dim3(256), 0, stream>>>(Vh, Vth);

    attn_pair<<<dim3(2048), dim3(128), 0, stream>>>(Qh, Kh, Vth, Oh);

    gemm_bt<true, float, 1><<<dim3(M_/128, E_/128, 1), dim3(256), 0, stream>>>(
        Oh, Woh, nullptr, nullptr, out, nullptr, nullptr, bo, M_, E_, E_);
}